// Round 5
// baseline (334.868 us; speedup 1.0000x reference)
//
#include <hip/hip_runtime.h>

#define LP  40    // k_support LDS row stride (shorts)
#define LPB 40    // k_main Bs row stride (shorts)

typedef __attribute__((ext_vector_type(8))) short short8;
typedef __attribute__((ext_vector_type(4))) short short4t;
typedef __attribute__((ext_vector_type(4))) float f32x4;

__device__ __forceinline__ short f2bf(float f) {
  unsigned u = __builtin_bit_cast(unsigned, f);
  u += 0x7FFFu + ((u >> 16) & 1u);   // round-to-nearest-even
  return (short)(u >> 16);
}

__device__ __forceinline__ float lrelu(float v) { return v >= 0.f ? v : 0.2f * v; }

// ---------------- Kernel 0: wT bf16 [512][512]  (wt[n][c] = w[c][n]) ----------------
__global__ __launch_bounds__(256) void k_wt(const float* __restrict__ w,
                                            short* __restrict__ wt) {
  __shared__ float t[64][65];
  int c0 = (blockIdx.x & 7) * 64;
  int n0 = (blockIdx.x >> 3) * 64;
  int r  = threadIdx.x >> 4;
  int q4 = (threadIdx.x & 15) * 4;
  for (int i = 0; i < 4; i++) {
    int c = r + i * 16;
    f32x4 v = *(const f32x4*)(w + (size_t)(c0 + c) * 512 + (n0 + q4));
    t[c][q4 + 0] = v[0]; t[c][q4 + 1] = v[1]; t[c][q4 + 2] = v[2]; t[c][q4 + 3] = v[3];
  }
  __syncthreads();
  for (int i = 0; i < 4; i++) {
    int n = r + i * 16;
    short4t o;
    for (int j = 0; j < 4; j++) o[j] = f2bf(t[q4 + j][n]);
    *(short4t*)(wt + (size_t)(n0 + n) * 512 + (c0 + q4)) = o;
  }
}

// ------------- Kernel 1: supportT bf16 [512][8192] = (inputs @ w + b)^T -------------
__global__ __launch_bounds__(512, 2) void k_support(const float* __restrict__ inp,
                                                    const short* __restrict__ wt,
                                                    const float* __restrict__ bias,
                                                    short* __restrict__ sup) {
  __shared__ __align__(16) short As[512 * LP];
  __shared__ __align__(16) short Bs[64 * LP];
  const int tid = threadIdx.x;
  const int m0 = blockIdx.x * 64;
  const int wave = tid >> 6, lane = tid & 63;
  const int wn = wave >> 1, wm = wave & 1;
  const int lr = lane & 15, lk = lane >> 4;
  const int bm = tid >> 3, bk = (tid & 7) * 4;
  f32x4 acc[8][2] = {};
  short8 ar[4]; f32x4 br;
  auto loadA = [&](int s) {
    const short* p = wt + (size_t)tid * 512 + s * 32;
    ar[0] = *(const short8*)(p);      ar[1] = *(const short8*)(p + 8);
    ar[2] = *(const short8*)(p + 16); ar[3] = *(const short8*)(p + 24);
  };
  auto loadB = [&](int s) {
    br = *(const f32x4*)(inp + (size_t)(m0 + bm) * 512 + s * 32 + bk);
  };
  loadA(0); loadB(0);
  for (int s = 0; s < 16; s++) {
    short* ad = As + tid * LP;
    *(short8*)(ad) = ar[0]; *(short8*)(ad + 8) = ar[1];
    *(short8*)(ad + 16) = ar[2]; *(short8*)(ad + 24) = ar[3];
    short4t bo;
    for (int j = 0; j < 4; j++) bo[j] = f2bf(br[j]);
    *(short4t*)(Bs + bm * LP + bk) = bo;
    __syncthreads();
    if (s + 1 < 16) { loadA(s + 1); loadB(s + 1); }
    short8 af[8], bfr[2];
    for (int nf = 0; nf < 8; nf++)
      af[nf] = *(const short8*)(As + (wn * 128 + nf * 16 + lr) * LP + lk * 8);
    for (int mf = 0; mf < 2; mf++)
      bfr[mf] = *(const short8*)(Bs + (wm * 32 + mf * 16 + lr) * LP + lk * 8);
    for (int nf = 0; nf < 8; nf++)
      for (int mf = 0; mf < 2; mf++)
        acc[nf][mf] = __builtin_amdgcn_mfma_f32_16x16x32_bf16(af[nf], bfr[mf], acc[nf][mf], 0, 0, 0);
    __syncthreads();
  }
  for (int nf = 0; nf < 8; nf++) {
    int nb = wn * 128 + nf * 16 + lk * 4;
    for (int mf = 0; mf < 2; mf++) {
      int m = m0 + wm * 32 + mf * 16 + lr;
      for (int j = 0; j < 4; j++) {
        int n = nb + j;
        sup[(size_t)n * 8192 + m] = f2bf(acc[nf][mf][j] + bias[n]);
      }
    }
  }
}

// ---- Kernel 2: BM=128, BN=512, BK=32. 1024 threads (16 waves: 8n x 2m), 1 blk/CU.
// ---- adj staged via global_load_lds into raw fp32 LDS dbuf (no staging VGPRs);
// ---- counted-vmcnt inline-asm barriers (T3/T4) keep gload(s+1)+af(s+1) in flight.
__global__ __launch_bounds__(1024, 4) void k_main(const float* __restrict__ adj,
                                                  const float* __restrict__ att,
                                                  const short* __restrict__ sup,
                                                  float* __restrict__ part,
                                                  float* __restrict__ outp,
                                                  int ksplit) {
  __shared__ __align__(16) float rawA[2][4 * 128 * 32];   // 2 x 64 KB: [mat][row][32k]
  __shared__ __align__(16) short Bs[2][128 * LPB];        // 20 KB
  const int tid = threadIdx.x;
  const int b = blockIdx.x;
  const int xpk = 8 / ksplit;
  const int xcd = b & 7;
  const int kc = xcd / xpk;                 // kc pinned to XCD pair -> sup slice L2-warm
  const int m0 = ((b >> 3) * xpk + (xcd % xpk)) * 128;
  const int kchunk = 8192 / ksplit;
  const int nsteps = kchunk / 32;           // 64 at ksplit=4 (pow2)
  const int kbase = kc * kchunk;
  const float t0 = att[0], t1 = att[1], t2 = att[2], t3 = att[3];
  const int w = tid >> 6, l = tid & 63;
  const int lr = l & 15, lk = l >> 4;
  const int n0w = (w >> 1) * 64;            // wave tile: 64n x 64m
  const int mw = (w & 1) * 64;
  const int crow = tid >> 3, coct = tid & 7;  // combine map: row 0..127, 16B-octant
  f32x4 acc[4][4] = {};                     // [nf][mf]
  const short* supbase = sup + (size_t)(n0w + lr) * 8192 + kbase + lk * 8;

  // gload chunk geometry: chunk c = w*4+i covers mat=c>>4, rows (c&15)*8..+8,
  // lane l -> row +(l>>3), floats (l&7)*4.. ; LDS dest = chunk*1024 + l*16 (linear).
  size_t gofs[4];
  int ldso[4];
#pragma unroll
  for (int i = 0; i < 4; i++) {
    int c = w * 4 + i;
    int mat = c >> 4, r0 = (c & 15) * 8;
    gofs[i] = ((size_t)mat << 26) + (size_t)(m0 + r0 + (l >> 3)) * 8192 + kbase + (l & 7) * 4;
    ldso[i] = c * 1024;
  }
  auto gl = [&](int i, int ss, int pp) {
    const float* g = adj + gofs[i] + (size_t)ss * 32;
    char* d = (char*)rawA[pp] + ldso[i];
    __builtin_amdgcn_global_load_lds(
        (const __attribute__((address_space(1))) unsigned*)g,
        (__attribute__((address_space(3))) unsigned*)d, 16, 0, 0);
  };

  // prologue: stage step 0
#pragma unroll
  for (int i = 0; i < 4; i++) gl(i, 0, 0);

  int p = 0;
  for (int s = 0; s < nsteps; s++) {
    // af(s) prefetch FIRST (oldest in vmcnt queue -> compiler wait never drains gloads)
    short8 af[4];
#pragma unroll
    for (int nf = 0; nf < 4; nf++)
      af[nf] = *(const short8*)(supbase + (size_t)(nf * 16) * 8192 + s * 32);
    __builtin_amdgcn_sched_barrier(0);
    // issue gload(s+1) into rawA[p^1] (wrapped dummy at s=nsteps-1 keeps counts uniform)
    int sn = (s + 1) & (nsteps - 1);
#pragma unroll
    for (int i = 0; i < 4; i++) gl(i, sn, p ^ 1);
    __builtin_amdgcn_sched_barrier(0);
    // own gload(s) done: exactly af(s)[4] + gload(s+1)[4] newer allowed
    asm volatile("s_waitcnt vmcnt(8)" ::: "memory");
    __builtin_amdgcn_sched_barrier(0);
    __builtin_amdgcn_s_barrier();           // all waves' gload(s) complete
    // combine 4 mats from rawA[p] (contiguous 1KB/wave ds_reads), write bf16 Bs[p]
    {
      const float* rb = rawA[p] + crow * 32 + coct * 4;
      f32x4 v0 = *(const f32x4*)(rb);
      f32x4 v1 = *(const f32x4*)(rb + 4096);
      f32x4 v2 = *(const f32x4*)(rb + 8192);
      f32x4 v3 = *(const f32x4*)(rb + 12288);
      short4t o;
#pragma unroll
      for (int e = 0; e < 4; e++)
        o[e] = f2bf(t0 * v0[e] + t1 * v1[e] + t2 * v2[e] + t3 * v3[e]);
      *(short4t*)(Bs[p] + crow * LPB + coct * 4) = o;
    }
    asm volatile("s_waitcnt lgkmcnt(0)" ::: "memory");
    __builtin_amdgcn_sched_barrier(0);
    __builtin_amdgcn_s_barrier();           // Bs[p] visible to all waves
    // MFMA phase: 16 x 16x16x32 per wave
    short8 bfr[4];
#pragma unroll
    for (int mf = 0; mf < 4; mf++)
      bfr[mf] = *(const short8*)(Bs[p] + (mw + mf * 16 + lr) * LPB + lk * 8);
#pragma unroll
    for (int nf = 0; nf < 4; nf++)
#pragma unroll
      for (int mf = 0; mf < 4; mf++)
        acc[nf][mf] = __builtin_amdgcn_mfma_f32_16x16x32_bf16(af[nf], bfr[mf], acc[nf][mf], 0, 0, 0);
    p ^= 1;
  }

#pragma unroll
  for (int nf = 0; nf < 4; nf++) {
    int n = n0w + nf * 16 + lk * 4;
#pragma unroll
    for (int mf = 0; mf < 4; mf++) {
      int m = m0 + mw + mf * 16 + lr;
      f32x4 v = acc[nf][mf];
      if (ksplit == 1) {
        for (int j = 0; j < 4; j++) v[j] = lrelu(v[j]);
        __builtin_nontemporal_store(v, (f32x4*)(outp + (size_t)m * 512 + n));
      } else {
        __builtin_nontemporal_store(v, (f32x4*)(part + ((size_t)kc << 22) + (size_t)m * 512 + n));
      }
    }
  }
}

// ---------------- Kernel 3: reduce K-split partials + LeakyReLU ----------------
__global__ __launch_bounds__(256) void k_reduce(const float* __restrict__ part,
                                                float* __restrict__ outp, int ksplit) {
  const size_t total = (size_t)8192 * 512 / 4;
  for (size_t i = (size_t)blockIdx.x * 256 + threadIdx.x; i < total;
       i += (size_t)gridDim.x * 256) {
    f32x4 a = __builtin_nontemporal_load((const f32x4*)(part + i * 4));
    for (int k = 1; k < ksplit; k++) {
      f32x4 bv = __builtin_nontemporal_load((const f32x4*)(part + ((size_t)k << 22) + i * 4));
      for (int j = 0; j < 4; j++) a[j] += bv[j];
    }
    f32x4 v;
    for (int j = 0; j < 4; j++) v[j] = lrelu(a[j]);
    __builtin_nontemporal_store(v, (f32x4*)(outp + i * 4));
  }
}

extern "C" void kernel_launch(void* const* d_in, const int* in_sizes, int n_in,
                              void* d_out, int out_size, void* d_ws, size_t ws_size,
                              hipStream_t stream) {
  const float* inputs = (const float*)d_in[0];
  const float* adj    = (const float*)d_in[1];
  const float* att    = (const float*)d_in[2];
  const float* w      = (const float*)d_in[3];
  const float* bias   = (const float*)d_in[4];
  float* outp = (float*)d_out;

  char* ws = (char*)d_ws;
  short* sup  = (short*)(ws);                 // 8 MB  supportT bf16 [512][8192]
  short* wt   = (short*)(ws + (8u << 20));    // 512 KB wT bf16 [512][512]
  float* part = (float*)(ws + (9u << 20));    // ksplit x 16 MB fp32 partials

  const size_t base = (9ull << 20), psz = (1ull << 24);
  int ksplit = 1;
  if (ws_size >= base + 4 * psz) ksplit = 4;
  else if (ws_size >= base + 2 * psz) ksplit = 2;

  k_wt<<<64, 256, 0, stream>>>(w, wt);
  k_support<<<128, 512, 0, stream>>>(inputs, wt, bias, sup);
  k_main<<<64 * ksplit, 1024, 0, stream>>>(adj, att, sup, part, outp, ksplit);
  if (ksplit > 1) k_reduce<<<1024, 256, 0, stream>>>(part, outp, ksplit);
}